// Round 11
// baseline (255.995 us; speedup 1.0000x reference)
//
#include <hip/hip_runtime.h>
#include <hip/hip_cooperative_groups.h>
#include <math.h>

namespace cg = cooperative_groups;

// Problem: scores = q[2048x768] @ p[16384x768]^T (fp32 in), per-query
// rank-of-target + log-softmax CE + Gaussian rank weight -> mean (scalar).
// R11: ONE cooperative mega-kernel (256 blocks = 1/CU at 129 KB LDS):
//   Stage A: cast q,p -> fp8 e4m3 + exact-fp32 s_t + out=0
//   grid.sync()
//   Stage B: R10 gemm core (best, 72 us): 256x256xBK128 dbuf fp8 MFMA,
//            pb-pinned XCD swizzle; each block runs 2 of the 512 tiles.
//   grid.sync()
//   Stage C: finalize (merge 256 chunks/query, weighted CE, mean).
// Rationale: gemm is at the m97-structure plateau (barrier vmcnt(0) drain,
// R5-R10 evidence); remaining ~90 us is non-gemm (prep + launch overhead).
// This isolates and removes the inter-dispatch component.

#define BQ 2048
#define DD 768
#define NPASS 8
#define PP 16384
#define BM 256
#define BN 256
#define BK 128
#define KITERS 6           // 768/128
#define NCHUNKS 256        // 64 nb * 4 wn-waves

#define NQ8   196608       // 2048*768/8
#define NTOT8 1769472      // (2048+16384)*768/8

#define ALPHA_C 2.6f
#define INV_2SIG2 (1.0f/6.48f)   // 1/(2*1.8^2)

typedef __attribute__((ext_vector_type(4))) float floatx4;  // MFMA C/D

__global__ __launch_bounds__(1024) void mega_kernel(const float* __restrict__ qf,
                                                    const float* __restrict__ pf,
                                                    unsigned char* __restrict__ qb,
                                                    unsigned char* __restrict__ pb,
                                                    float* __restrict__ st,
                                                    float* __restrict__ pm,
                                                    float* __restrict__ pl,
                                                    float* __restrict__ pc,
                                                    float* __restrict__ out) {
  __shared__ unsigned char As[2][32 * 1024];   // [buf][rowgrp*2+kh unit][1 KB]
  __shared__ unsigned char Bs[2][32 * 1024];
  __shared__ float st_lds[BM];
  __shared__ float red[8];

  cg::grid_group grid = cg::this_grid();

  const int t = threadIdx.x;
  const int lane = t & 63;
  const int wv = t >> 6;            // 0..15
  const int bid = blockIdx.x;       // 0..255

  // ================= Stage A: cast + s_t + out zero =================
  if (bid == 0 && t == 0) *out = 0.f;
  {
    uint2* qb2 = (uint2*)qb;
    uint2* pb2 = (uint2*)pb;
    for (int i = bid * 1024 + t; i < NTOT8; i += 256 * 1024) {
      const float4* src; uint2* dst;
      if (i < NQ8) { src = (const float4*)qf + 2 * (size_t)i; dst = qb2 + i; }
      else { const size_t j = (size_t)i - NQ8; src = (const float4*)pf + 2 * j; dst = pb2 + j; }
      const float4 a = src[0], c = src[1];
      unsigned lo = __builtin_amdgcn_cvt_pk_fp8_f32(a.x, a.y, 0, 0);
      lo = __builtin_amdgcn_cvt_pk_fp8_f32(a.z, a.w, lo, 1);
      unsigned hi = __builtin_amdgcn_cvt_pk_fp8_f32(c.x, c.y, 0, 0);
      hi = __builtin_amdgcn_cvt_pk_fp8_f32(c.z, c.w, hi, 1);
      uint2 w; w.x = lo; w.y = hi;
      *dst = w;
    }
    if (wv < 8) {   // s_t: 8 queries per block, 1 wave each (exact fp32)
      const int qi = bid * 8 + wv;
      const float4* q4 = (const float4*)(qf + (size_t)qi * DD);
      const float4* p4 = (const float4*)(pf + (size_t)qi * NPASS * DD);
      float acc = 0.f;
#pragma unroll
      for (int u = 0; u < 3; ++u) {   // 192 float4 per row = 64 lanes * 3
        float4 a = q4[lane + 64 * u];
        float4 c = p4[lane + 64 * u];
        acc = fmaf(a.x, c.x, acc);
        acc = fmaf(a.y, c.y, acc);
        acc = fmaf(a.z, c.z, acc);
        acc = fmaf(a.w, c.w, acc);
      }
#pragma unroll
      for (int off = 32; off >= 1; off >>= 1) acc += __shfl_xor(acc, off);
      if (lane == 0) st[qi] = acc;
    }
  }

  grid.sync();

  // ================= Stage B: fp8 MFMA GEMM (R10 core), 2 tiles/block =====
  const int wm = wv >> 2, wn = wv & 3;
  const int lm = lane & 15;
  const int lq = lane >> 4;
  const int lds_lane = lane * 16;

  for (int half = 0; half < 2; ++half) {
    const int bid2 = half * 256 + bid;          // 0..511 tile id
    const int xcd = bid2 & 7;                   // round-robin XCD assignment
    const int nb = xcd * 8 + ((bid2 >> 3) & 7); // XCD-private pb slice (1.6 MB)
    const int mb = bid2 >> 6;                   // 0..7
    const int qbase = mb * BM;
    const int n0 = nb * BN;

    __syncthreads();   // protect st_lds/As from previous half's readers
    if (t < BM) st_lds[t] = st[qbase + t];

    floatx4 acc[4][4];
#pragma unroll
    for (int i = 0; i < 4; ++i)
#pragma unroll
      for (int j = 0; j < 4; ++j) acc[i][j] = (floatx4){0.f, 0.f, 0.f, 0.f};

    const size_t arow = (size_t)(qbase + wv * 16 + lm) * DD;
    const size_t brow = (size_t)(n0 + wv * 16 + lm) * DD;

#define STAGE(KT, BUF)                                                          \
    {                                                                           \
      const size_t koff = (size_t)(KT) * BK + lq * 16;                          \
      _Pragma("unroll")                                                         \
      for (int kh = 0; kh < 2; ++kh) {                                          \
        __builtin_amdgcn_global_load_lds(                                       \
            (const __attribute__((address_space(1))) void*)(qb + arow + koff + kh * 64), \
            (__attribute__((address_space(3))) void*)(&As[BUF][(wv * 2 + kh) * 1024] + lds_lane), \
            16, 0, 0);                                                          \
        __builtin_amdgcn_global_load_lds(                                       \
            (const __attribute__((address_space(1))) void*)(pb + brow + koff + kh * 64), \
            (__attribute__((address_space(3))) void*)(&Bs[BUF][(wv * 2 + kh) * 1024] + lds_lane), \
            16, 0, 0);                                                          \
      }                                                                         \
    }

    STAGE(0, 0)
    for (int kt = 0; kt < KITERS; ++kt) {
      const int cb = kt & 1;
      __syncthreads();                 // drains vmcnt -> buf cb ready
      if (kt < KITERS - 1) STAGE(kt + 1, cb ^ 1)   // flies under compute below
#pragma unroll
      for (int ks = 0; ks < 4; ++ks) {
        const int kh = ks >> 1;
        const int intra = ((ks & 1) * 2 + (lq >> 1)) * 256 + lm * 16 + (lq & 1) * 8;
        long a[4], b[4];
#pragma unroll
        for (int i = 0; i < 4; ++i)
          a[i] = *(const long*)(&As[cb][((wm * 4 + i) * 2 + kh) * 1024] + intra);
#pragma unroll
        for (int j = 0; j < 4; ++j)
          b[j] = *(const long*)(&Bs[cb][((wn * 4 + j) * 2 + kh) * 1024] + intra);
#pragma unroll
        for (int i = 0; i < 4; ++i)
#pragma unroll
          for (int j = 0; j < 4; ++j)
            acc[i][j] = __builtin_amdgcn_mfma_f32_16x16x32_fp8_fp8(a[i], b[j], acc[i][j], 0, 0, 0);
      }
    }
#undef STAGE

    // ---- fused epilogue: per-row max / sumexp / count over this 64-col group
#pragma unroll
    for (int i = 0; i < 4; ++i) {
#pragma unroll
      for (int r = 0; r < 4; ++r) {
        const int rl = wm * 64 + i * 16 + lq * 4 + r;   // local query row
        float mx = fmaxf(fmaxf(acc[i][0][r], acc[i][1][r]),
                         fmaxf(acc[i][2][r], acc[i][3][r]));
#pragma unroll
        for (int off = 1; off <= 8; off <<= 1) mx = fmaxf(mx, __shfl_xor(mx, off));
        const float stv = st_lds[rl];
        const int qg = qbase + rl;
        const int tcol = qg * NPASS;
        float sum = 0.f, c = 0.f;
#pragma unroll
        for (int j = 0; j < 4; ++j) {
          const float s = acc[i][j][r];
          sum += __expf(s - mx);
          const int cg = n0 + wn * 64 + j * 16 + lm;
          if (s > stv && cg != tcol) c += 1.f;
        }
#pragma unroll
        for (int off = 1; off <= 8; off <<= 1) {
          sum += __shfl_xor(sum, off);
          c += __shfl_xor(c, off);
        }
        if (lm == 0) {
          const int chunk = nb * 4 + wn;
          const size_t idx = (size_t)qg * NCHUNKS + chunk;
          pm[idx] = mx; pl[idx] = sum; pc[idx] = c;
        }
      }
    }
  }

  grid.sync();

  // ================= Stage C: finalize (8 queries/block, 1 wave each) =====
  float loss = 0.f;
  if (wv < 8) {
    const int qi = bid * 8 + wv;
    float4 m4 = ((const float4*)(pm + (size_t)qi * NCHUNKS))[lane];
    float mx = fmaxf(fmaxf(m4.x, m4.y), fmaxf(m4.z, m4.w));
#pragma unroll
    for (int off = 32; off >= 1; off >>= 1) mx = fmaxf(mx, __shfl_xor(mx, off));
    float4 l4 = ((const float4*)(pl + (size_t)qi * NCHUNKS))[lane];
    float4 c4 = ((const float4*)(pc + (size_t)qi * NCHUNKS))[lane];
    float l = l4.x * __expf(m4.x - mx) + l4.y * __expf(m4.y - mx) +
              l4.z * __expf(m4.z - mx) + l4.w * __expf(m4.w - mx);
    float c = c4.x + c4.y + c4.z + c4.w;
#pragma unroll
    for (int off = 32; off >= 1; off >>= 1) {
      l += __shfl_xor(l, off);
      c += __shfl_xor(c, off);
    }
    if (lane == 0) {
      const float raw = logf(l) + mx - st[qi];   // -log_softmax[target]
      const float dr = c - 1.0f;                 // rank - OPTIMAL_RANK
      const float w = 1.0f + ALPHA_C * __expf(-(dr * dr) * INV_2SIG2);
      loss = raw * w * (1.0f / (float)BQ);
    }
  }
  __syncthreads();   // all waves past stage B partial reads; red[] safe
  if (wv < 8 && lane == 0) red[wv] = loss;
  __syncthreads();
  if (t == 0) {
    float s = 0.f;
#pragma unroll
    for (int i = 0; i < 8; ++i) s += red[i];
    atomicAdd(out, s);
  }
}

// ---------------------------------------------------------------------------
extern "C" void kernel_launch(void* const* d_in, const int* in_sizes, int n_in,
                              void* d_out, int out_size, void* d_ws, size_t ws_size,
                              hipStream_t stream) {
  const float* q = (const float*)d_in[0];
  const float* p = (const float*)d_in[1];
  char* ws = (char*)d_ws;
  unsigned char* qb = (unsigned char*)ws;                  // 1,572,864 B
  unsigned char* pb = (unsigned char*)(ws + 1572864);      // 12,582,912 B
  float* st = (float*)(ws + 14155776);                     // 8 KB
  float* pm = (float*)(ws + 14163968);                     // 2 MB
  float* pl = (float*)(ws + 16261120);                     // 2 MB
  float* pc = (float*)(ws + 18358272);                     // 2 MB (end ~20.5 MB)
  float* out = (float*)d_out;

  void* args[] = {(void*)&q, (void*)&p, (void*)&qb, (void*)&pb,
                  (void*)&st, (void*)&pm, (void*)&pl, (void*)&pc, (void*)&out};
  hipLaunchCooperativeKernel((const void*)mega_kernel, dim3(256), dim3(1024),
                             args, 0, stream);
}

// Round 12
// 176.943 us; speedup vs baseline: 1.4468x; 1.4468x over previous
//
#include <hip/hip_runtime.h>
#include <math.h>

// Problem: scores = q[2048x768] @ p[16384x768]^T (fp32 in), per-query
// rank-of-target + log-softmax CE + Gaussian rank weight -> mean (scalar).
// R12: PRODUCER/CONSUMER WAVE SPECIALIZATION on the fp8 MFMA GEMM.
// 16 waves: 8 consumers (4 wm x 2 wn, tile 256x128, zero in-loop VMEM ->
// pre-barrier vmcnt(0) free) + 8 producers (6 global_load_lds each into the
// next 48-KB buffer; drain only their own fresh loads, hidden under the
// consumers' MFMA phase). This is the one K-loop restructure not covered by
// the m131-m141 failures (all had every wave load+compute).
// R11 lesson: ~87-92 us of dur_us is harness reset (d_in restore + ws
// poison) — immovable; prep+finalize are only ~5 us. gemm is the lever.
// Swizzle: xcd=bid&7 owns 16 nb-tiles (1.5 MB pb slice) + qb (1.5 MB) < 4MB L2.

#define BQ 2048
#define DD 768
#define NPASS 8
#define PP 16384
#define BM 256
#define BN 128
#define BK 128
#define KITERS 6           // 768/128
#define NBLK 128           // PP/BN
#define MBLK 8             // BQ/BM
#define NCHUNKS 256        // NBLK * 2 wn-groups

#define ALPHA_C 2.6f
#define INV_2SIG2 (1.0f/6.48f)   // 1/(2*1.8^2)

typedef __attribute__((ext_vector_type(4))) float floatx4;  // MFMA C/D

// ---------------------------------------------------------------------------
// Kernel 1 (fused): cast q,p -> fp8 e4m3  +  s_t exact-fp32 dots  +  out=0.
// ---------------------------------------------------------------------------
#define NQ8   196608     // 2048*768/8
#define NTOT8 1769472    // (2048+16384)*768/8
#define NCB   6912       // NTOT8/256
__global__ __launch_bounds__(256) void prep_kernel(const float* __restrict__ qf,
                                                   const float* __restrict__ pf,
                                                   uint2* __restrict__ qb,
                                                   uint2* __restrict__ pb,
                                                   float* __restrict__ st,
                                                   float* __restrict__ out) {
  const int b = blockIdx.x;
  if (b == 0 && threadIdx.x == 0) *out = 0.f;
  if (b < NCB) {
    const int i = b * 256 + threadIdx.x;        // float8 index
    const float4* src; uint2* dst;
    if (i < NQ8) { src = (const float4*)qf + 2 * (size_t)i; dst = qb + i; }
    else { const size_t j = (size_t)i - NQ8; src = (const float4*)pf + 2 * j; dst = pb + j; }
    const float4 a = src[0], c = src[1];
    unsigned lo = __builtin_amdgcn_cvt_pk_fp8_f32(a.x, a.y, 0, 0);
    lo = __builtin_amdgcn_cvt_pk_fp8_f32(a.z, a.w, lo, 1);
    unsigned hi = __builtin_amdgcn_cvt_pk_fp8_f32(c.x, c.y, 0, 0);
    hi = __builtin_amdgcn_cvt_pk_fp8_f32(c.z, c.w, hi, 1);
    uint2 w; w.x = lo; w.y = hi;
    *dst = w;
  } else {
    const int wv = threadIdx.x >> 6, lane = threadIdx.x & 63;
    const int qi = (b - NCB) * 4 + wv;
    const float4* q4 = (const float4*)(qf + (size_t)qi * DD);
    const float4* p4 = (const float4*)(pf + (size_t)qi * NPASS * DD);
    float acc = 0.f;
#pragma unroll
    for (int u = 0; u < 3; ++u) {   // 192 float4 per row = 64 lanes * 3
      float4 a = q4[lane + 64 * u];
      float4 c = p4[lane + 64 * u];
      acc = fmaf(a.x, c.x, acc);
      acc = fmaf(a.y, c.y, acc);
      acc = fmaf(a.z, c.z, acc);
      acc = fmaf(a.w, c.w, acc);
    }
#pragma unroll
    for (int off = 32; off >= 1; off >>= 1) acc += __shfl_xor(acc, off);
    if (lane == 0) st[qi] = acc;
  }
}

// ---------------------------------------------------------------------------
// Kernel 2: wave-specialized fp8 MFMA GEMM 256x128, BK=128 dbuf (96 KB LDS).
// Waves 0..7: consumers (wm=wv>>1 in 0..3, wn=wv&1), 4x4 frags of 16x16x32
//   each (64x64 out), ZERO in-loop VMEM.
// Waves 8..15: producers; per phase 6 global_load_lds (1 KB units) into the
//   next buffer. Units: 0..31 = A (rowgrp=u>>1, kh=u&1), 32..47 = B.
// LDS unit = 16 rows x 64 k-bytes at u*1024; lane(lm,lq) stages row lm,
// k-bytes lq*16 (wave-uniform base + lane*16). Frag intra (validated R4-R11):
//   k = ks*32+lq*8+j -> ((ks&1)*2+(lq>>1))*256 + lm*16 + (lq&1)*8, kh=ks>>1.
// C/D: col=lane&15, row=(lane>>4)*4+reg.
// Dbuf safety: phase kt computes buf kt&1 (producer loads drained at the
// phase-entry barrier by the producers' own vmcnt(0)); producers fill
// (kt+1)&1, whose previous readers finished before barrier kt (lgkmcnt(0)).
// ---------------------------------------------------------------------------
__global__ __launch_bounds__(1024) void gemm_kernel(const unsigned char* __restrict__ qb,
                                                    const unsigned char* __restrict__ pb,
                                                    const float* __restrict__ st,
                                                    float* __restrict__ pm,
                                                    float* __restrict__ pl,
                                                    float* __restrict__ pc) {
  __shared__ unsigned char As[2][32 * 1024];   // [buf][A unit][1 KB] = 64 KB
  __shared__ unsigned char Bs[2][16 * 1024];   // [buf][B unit][1 KB] = 32 KB
  __shared__ float st_lds[BM];

  const int t = threadIdx.x;
  const int lane = t & 63;
  const int wv = t >> 6;            // 0..15
  const int bid = blockIdx.x;       // 0..1023
  const int xcd = bid & 7;
  const int nb = xcd * 16 + ((bid >> 3) & 15);   // XCD-private pb slice (1.5 MB)
  const int mb = bid >> 7;                       // 0..7
  const int qbase = mb * BM;
  const int n0 = nb * BN;
  const int lm = lane & 15;
  const int lq = lane >> 4;
  const int lds_lane = lane * 16;
  const bool producer = (wv >= 8);
  const int pw = wv - 8;            // producer index 0..7

  if (t < BM) st_lds[t] = st[qbase + t];   // consumer waves 0..3; drained @bar0

  // producer stage of one phase into buffer BUF: units pw*6 .. pw*6+6
#define STAGE(KT, BUF)                                                          \
  {                                                                             \
    _Pragma("unroll")                                                           \
    for (int s = 0; s < 6; ++s) {                                               \
      const int u = pw * 6 + s;                                                 \
      const int isB = (u >= 32);                                                \
      const int ul = isB ? (u - 32) : u;                                        \
      const int rowg = ul >> 1, kh = ul & 1;                                    \
      const size_t g = (size_t)((isB ? n0 : qbase) + rowg * 16 + lm) * DD       \
                       + (size_t)(KT) * BK + kh * 64 + lq * 16;                 \
      unsigned char* dst = (isB ? &Bs[BUF][ul * 1024] : &As[BUF][ul * 1024]);   \
      __builtin_amdgcn_global_load_lds(                                         \
          (const __attribute__((address_space(1))) void*)((isB ? pb : qb) + g), \
          (__attribute__((address_space(3))) void*)(dst + lds_lane), 16, 0, 0); \
    }                                                                           \
  }

  floatx4 acc[4][4];
#pragma unroll
  for (int i = 0; i < 4; ++i)
#pragma unroll
    for (int j = 0; j < 4; ++j) acc[i][j] = (floatx4){0.f, 0.f, 0.f, 0.f};

  const int wm = wv >> 1, wn = wv & 1;   // consumer mapping (wv 0..7)

  if (producer) STAGE(0, 0)
  for (int kt = 0; kt < KITERS; ++kt) {
    const int cb = kt & 1;
    __syncthreads();   // producers drained buf cb's loads before arriving
    if (producer) {
      if (kt < KITERS - 1) STAGE(kt + 1, cb ^ 1)
    } else {
#pragma unroll
      for (int ks = 0; ks < 4; ++ks) {
        const int kh = ks >> 1;
        const int intra = ((ks & 1) * 2 + (lq >> 1)) * 256 + lm * 16 + (lq & 1) * 8;
        long a[4], b[4];
#pragma unroll
        for (int i = 0; i < 4; ++i)
          a[i] = *(const long*)(&As[cb][((wm * 4 + i) * 2 + kh) * 1024] + intra);
#pragma unroll
        for (int j = 0; j < 4; ++j)
          b[j] = *(const long*)(&Bs[cb][((wn * 4 + j) * 2 + kh) * 1024] + intra);
#pragma unroll
        for (int i = 0; i < 4; ++i)
#pragma unroll
          for (int j = 0; j < 4; ++j)
            acc[i][j] = __builtin_amdgcn_mfma_f32_16x16x32_fp8_fp8(a[i], b[j], acc[i][j], 0, 0, 0);
      }
    }
  }
#undef STAGE

  // ---- fused epilogue (consumers only): per-row max/sumexp/count, 64 cols --
  if (!producer) {
#pragma unroll
    for (int i = 0; i < 4; ++i) {
#pragma unroll
      for (int r = 0; r < 4; ++r) {
        const int rl = wm * 64 + i * 16 + lq * 4 + r;   // local query row
        float mx = fmaxf(fmaxf(acc[i][0][r], acc[i][1][r]),
                         fmaxf(acc[i][2][r], acc[i][3][r]));
#pragma unroll
        for (int off = 1; off <= 8; off <<= 1) mx = fmaxf(mx, __shfl_xor(mx, off));
        const float stv = st_lds[rl];
        const int qg = qbase + rl;
        const int tcol = qg * NPASS;
        float sum = 0.f, c = 0.f;
#pragma unroll
        for (int j = 0; j < 4; ++j) {
          const float s = acc[i][j][r];
          sum += __expf(s - mx);
          const int cg = n0 + wn * 64 + j * 16 + lm;
          if (s > stv && cg != tcol) c += 1.f;
        }
#pragma unroll
        for (int off = 1; off <= 8; off <<= 1) {
          sum += __shfl_xor(sum, off);
          c += __shfl_xor(c, off);
        }
        if (lm == 0) {
          const int chunk = nb * 2 + wn;
          const size_t idx = (size_t)qg * NCHUNKS + chunk;
          pm[idx] = mx; pl[idx] = sum; pc[idx] = c;
        }
      }
    }
  }
}

// ---------------------------------------------------------------------------
// Kernel 3: merge 256 chunks/query, weighted CE, mean -> atomicAdd. 1 wave/query.
// ---------------------------------------------------------------------------
__global__ __launch_bounds__(256) void finalize_kernel(const float* __restrict__ st,
                                                       const float* __restrict__ pm,
                                                       const float* __restrict__ pl,
                                                       const float* __restrict__ pc,
                                                       float* __restrict__ out) {
  const int wv = threadIdx.x >> 6, lane = threadIdx.x & 63;
  const int qi = blockIdx.x * 4 + wv;
  float4 m4 = ((const float4*)(pm + (size_t)qi * NCHUNKS))[lane];
  float mx = fmaxf(fmaxf(m4.x, m4.y), fmaxf(m4.z, m4.w));
#pragma unroll
  for (int off = 32; off >= 1; off >>= 1) mx = fmaxf(mx, __shfl_xor(mx, off));
  float4 l4 = ((const float4*)(pl + (size_t)qi * NCHUNKS))[lane];
  float4 c4 = ((const float4*)(pc + (size_t)qi * NCHUNKS))[lane];
  float l = l4.x * __expf(m4.x - mx) + l4.y * __expf(m4.y - mx) +
            l4.z * __expf(m4.z - mx) + l4.w * __expf(m4.w - mx);
  float c = c4.x + c4.y + c4.z + c4.w;
#pragma unroll
  for (int off = 32; off >= 1; off >>= 1) {
    l += __shfl_xor(l, off);
    c += __shfl_xor(c, off);
  }
  float loss = 0.f;
  if (lane == 0) {
    const float raw = logf(l) + mx - st[qi];   // -log_softmax[target]
    const float dr = c - 1.0f;                 // rank - OPTIMAL_RANK
    const float w = 1.0f + ALPHA_C * __expf(-(dr * dr) * INV_2SIG2);
    loss = raw * w * (1.0f / (float)BQ);
  }
  __shared__ float red[4];
  if (lane == 0) red[wv] = loss;
  __syncthreads();
  if (threadIdx.x == 0) atomicAdd(out, red[0] + red[1] + red[2] + red[3]);
}

// ---------------------------------------------------------------------------
extern "C" void kernel_launch(void* const* d_in, const int* in_sizes, int n_in,
                              void* d_out, int out_size, void* d_ws, size_t ws_size,
                              hipStream_t stream) {
  const float* q = (const float*)d_in[0];
  const float* p = (const float*)d_in[1];
  char* ws = (char*)d_ws;
  unsigned char* qb = (unsigned char*)ws;                  // 1,572,864 B
  unsigned char* pb = (unsigned char*)(ws + 1572864);      // 12,582,912 B
  float* st = (float*)(ws + 14155776);                     // 8 KB
  float* pm = (float*)(ws + 14163968);                     // 2 MB
  float* pl = (float*)(ws + 16261120);                     // 2 MB
  float* pc = (float*)(ws + 18358272);                     // 2 MB (end ~20.5 MB)
  float* out = (float*)d_out;

  prep_kernel<<<NCB + BQ / 4, 256, 0, stream>>>(q, p, (uint2*)qb, (uint2*)pb, st, out);
  gemm_kernel<<<NBLK * MBLK, 1024, 0, stream>>>(qb, pb, st, pm, pl, pc);
  finalize_kernel<<<BQ / 4, 256, 0, stream>>>(st, pm, pl, pc, out);
}